// Round 8
// baseline (83.139 us; speedup 1.0000x reference)
//
#include <hip/hip_runtime.h>
#include <hip/hip_bf16.h>

// Analytic reduction of the reference:
//   angles = pi*tanh(MLP(x));  <Z0> = sin(theta1)*sin(theta2)  (theta0, q_params cancel)
//   out = sigmoid(5*<Z0>)
// Memory-bound on streaming x (205 MB). Round 8 = R3 structure (best, 47.5us) +
//   (a) v_cvt_pk_bf16_f32 packing via __float22bfloat162_rn,
//   (b) nontemporal loads on x via ext_vector f32x4 (the builtin rejects
//       HIP_vector_type float4 -- R7 compile fix).

#define KDIM 784
#define BMB 256
#define NSTEP 25          // ceil(784/32); step 24 is a half tile (k=768..783)
#define H1STR 66          // h1 LDS stride (words): 2-way banks (free)

using f32x4 = __attribute__((ext_vector_type(4))) float;
using s16x8 = __attribute__((ext_vector_type(8))) short;

#define NTL(p) __builtin_nontemporal_load((const f32x4*)(p))

union LdsU {
    uint4 bfr[NSTEP * 4 * 64];            // 102400 B: W1 frags [step][n][lane]
    struct {
        float h1[BMB * H1STR];            // 67584 B
        float part[4][BMB][2];            // 8192 B
    } t;
};

__device__ __forceinline__ uint4 pack8(f32x4 a, f32x4 b) {
    union { __hip_bfloat162 h[4]; uint4 u; } c;
    c.h[0] = __float22bfloat162_rn(make_float2(a.x, a.y));   // v_cvt_pk_bf16_f32
    c.h[1] = __float22bfloat162_rn(make_float2(a.z, a.w));
    c.h[2] = __float22bfloat162_rn(make_float2(b.x, b.y));
    c.h[3] = __float22bfloat162_rn(make_float2(b.z, b.w));
    return c.u;
}
__device__ __forceinline__ s16x8 asfrag(uint4 p) {
    union { uint4 u; s16x8 s; } c; c.u = p; return c.s;
}

__global__ void __launch_bounds__(1024, 4) hybrid_kernel(
    const float* __restrict__ x, const float* __restrict__ W1,
    const float* __restrict__ b1, const float* __restrict__ W2,
    const float* __restrict__ b2, const float* __restrict__ W3,
    const float* __restrict__ b3, float* __restrict__ out, int B)
{
    __shared__ LdsU lds;
    const int tid  = threadIdx.x;
    const int wave = tid >> 6, lane = tid & 63;
    const int row0 = blockIdx.x * BMB;

    // A addressing: lane owns row (wave*16 + (lane&15)), k-offset (lane>>4)*8
    const int kl = (lane >> 4) << 3;
    int arow = row0 + wave * 16 + (lane & 15);
    arow = arow < B ? arow : B - 1;                  // B % 256 == 0 in practice
    const float* abase = x + (size_t)arow * KDIM + kl;

    const f32x4 z4 = {0.f, 0.f, 0.f, 0.f};

    // issue step-0 A loads first: in flight during W1 staging
    f32x4 c0 = NTL(abase);
    f32x4 c1 = NTL(abase + 4);

    // stage W1 -> LDS in B-frag order: chunk c = (step, n, lane16B)
    for (int c = tid; c < NSTEP * 4 * 64; c += 1024) {
        int s = c >> 8, n = (c >> 6) & 3, l = c & 63;
        int k0  = s * 32 + ((l >> 4) << 3);
        int col = n * 16 + (l & 15);
        f32x4 w0 = z4, w1 = z4;
        if (k0 < KDIM) {                             // tail zero-fill (784%8==0)
            const float* p = W1 + (size_t)col * KDIM + k0;
            w0 = *(const f32x4*)p;
            w1 = *(const f32x4*)(p + 4);
        }
        lds.bfr[c] = pack8(w0, w1);
    }

    f32x4 acc[4];
    #pragma unroll
    for (int n = 0; n < 4; ++n)
        #pragma unroll
        for (int j = 0; j < 4; ++j) acc[n][j] = 0.f;

    // raw barrier: drain only LDS writes; A loads stay in flight
    asm volatile("s_waitcnt lgkmcnt(0)" ::: "memory");
    __builtin_amdgcn_s_barrier();
    __builtin_amdgcn_sched_barrier(0);

    // barrier-free main loop: global->reg A, LDS B (read-only), 4 MFMA / step
    #define STEP(s, u0, u1)                                                        \
        {                                                                          \
            s16x8 af = asfrag(pack8(u0, u1));                                      \
            const uint4* bp = &lds.bfr[(s) * 256 + lane];                          \
            _Pragma("unroll")                                                      \
            for (int n = 0; n < 4; ++n)                                            \
                acc[n] = __builtin_amdgcn_mfma_f32_16x16x32_bf16(                  \
                    af, asfrag(bp[n * 64]), acc[n], 0, 0, 0);                      \
        }

    for (int s = 0; s < 23; ++s) {                   // prefetch s+1 unguarded
        f32x4 n0 = NTL(abase + (s + 1) * 32);
        f32x4 n1 = NTL(abase + (s + 1) * 32 + 4);
        STEP(s, c0, c1);
        c0 = n0; c1 = n1;
    }
    {                                                // s=23: guarded prefetch of 24
        f32x4 n0 = z4, n1 = z4;
        if (kl < KDIM - 768) {                       // lanes with k<784 only
            n0 = NTL(abase + 768);
            n1 = NTL(abase + 772);
        }
        STEP(23, c0, c1);
        c0 = n0; c1 = n1;
    }
    STEP(24, c0, c1);
    #undef STEP

    __syncthreads();                                 // all B-frag reads done; reuse LDS

    // h1 = relu(acc + b1); C layout (m89): col = n*16+(lane&15), row = (lane>>4)*4+j
    #pragma unroll
    for (int n = 0; n < 4; ++n) {
        int c = n * 16 + (lane & 15);
        float bias = b1[c];
        #pragma unroll
        for (int j = 0; j < 4; ++j) {
            int r = wave * 16 + (lane >> 4) * 4 + j;
            lds.t.h1[r * H1STR + c] = fmaxf(acc[n][j] + bias, 0.f);
        }
    }
    __syncthreads();

    // layers 2+3: row = tid&255, q = tid>>8 (wave-uniform)
    {
        const int row = tid & 255, q = tid >> 8;
        const float* h1p = &lds.t.h1[row * H1STR];
        f32x4 hv[16];
        #pragma unroll
        for (int k4 = 0; k4 < 16; ++k4) hv[k4] = *(const f32x4*)(h1p + k4 * 4);
        float a1 = 0.f, a2 = 0.f;
        #pragma unroll
        for (int jj = 0; jj < 4; ++jj) {
            int j2 = q * 4 + jj;
            float s = b2[j2];
            #pragma unroll
            for (int k4 = 0; k4 < 16; ++k4) {
                const f32x4 w = *(const f32x4*)(W2 + j2 * 64 + k4 * 4);
                s = fmaf(hv[k4].x, w.x, s); s = fmaf(hv[k4].y, w.y, s);
                s = fmaf(hv[k4].z, w.z, s); s = fmaf(hv[k4].w, w.w, s);
            }
            s = fmaxf(s, 0.f);
            a1 = fmaf(s, W3[16 + j2], a1);
            a2 = fmaf(s, W3[32 + j2], a2);
        }
        lds.t.part[q][row][0] = a1;
        lds.t.part[q][row][1] = a2;
    }
    __syncthreads();

    if (tid < BMB) {
        int grow = row0 + tid;
        if (grow < B) {
            float a1 = b3[1] + lds.t.part[0][tid][0] + lds.t.part[1][tid][0]
                             + lds.t.part[2][tid][0] + lds.t.part[3][tid][0];
            float a2 = b3[2] + lds.t.part[0][tid][1] + lds.t.part[1][tid][1]
                             + lds.t.part[2][tid][1] + lds.t.part[3][tid][1];
            float t1 = 1.f - 2.f / (__expf(2.f * a1) + 1.f);   // tanh
            float t2 = 1.f - 2.f / (__expf(2.f * a2) + 1.f);
            const float PI = 3.14159265358979323846f;
            float z0 = __sinf(PI * t1) * __sinf(PI * t2);
            out[grow] = 1.f / (1.f + __expf(-5.f * z0));
        }
    }
}

extern "C" void kernel_launch(void* const* d_in, const int* in_sizes, int n_in,
                              void* d_out, int out_size, void* d_ws, size_t ws_size,
                              hipStream_t stream) {
    const float* x  = (const float*)d_in[0];
    const float* W1 = (const float*)d_in[1];
    const float* b1 = (const float*)d_in[2];
    const float* W2 = (const float*)d_in[3];
    const float* b2 = (const float*)d_in[4];
    const float* W3 = (const float*)d_in[5];
    const float* b3 = (const float*)d_in[6];
    // d_in[7] = q_params: unused (RZ phases cancel in |psi|^2)
    int B = in_sizes[0] / KDIM;
    int grid = (B + BMB - 1) / BMB;
    hybrid_kernel<<<grid, 1024, 0, stream>>>(x, W1, b1, W2, b2, W3, b3, (float*)d_out, B);
}

// Round 9
// 49.776 us; speedup vs baseline: 1.6702x; 1.6702x over previous
//
#include <hip/hip_runtime.h>
#include <hip/hip_bf16.h>

// Analytic reduction of the reference:
//   angles = pi*tanh(MLP(x));  <Z0> = sin(theta1)*sin(theta2)  (theta0, q_params cancel)
//   out = sigmoid(5*<Z0>)
// Memory-bound on streaming x (205 MB). Round 9 = R3 structure (best, 47.5us) +
//   v_cvt_pk_bf16_f32 packing ONLY (R8 showed nontemporal loads defeat L2
//   request coalescing on this scattered pattern: 83us. Unbundled.)

#define KDIM 784
#define BMB 256
#define NSTEP 25          // ceil(784/32); step 24 is a half tile (k=768..783)
#define H1STR 66          // h1 LDS stride (words): 2-way banks (free)

using f32x4 = __attribute__((ext_vector_type(4))) float;
using s16x8 = __attribute__((ext_vector_type(8))) short;

union LdsU {
    uint4 bfr[NSTEP * 4 * 64];            // 102400 B: W1 frags [step][n][lane]
    struct {
        float h1[BMB * H1STR];            // 67584 B
        float part[4][BMB][2];            // 8192 B
    } t;
};

__device__ __forceinline__ uint4 pack8(f32x4 a, f32x4 b) {
    union { __hip_bfloat162 h[4]; uint4 u; } c;
    c.h[0] = __float22bfloat162_rn(make_float2(a.x, a.y));   // v_cvt_pk_bf16_f32
    c.h[1] = __float22bfloat162_rn(make_float2(a.z, a.w));
    c.h[2] = __float22bfloat162_rn(make_float2(b.x, b.y));
    c.h[3] = __float22bfloat162_rn(make_float2(b.z, b.w));
    return c.u;
}
__device__ __forceinline__ s16x8 asfrag(uint4 p) {
    union { uint4 u; s16x8 s; } c; c.u = p; return c.s;
}

__global__ void __launch_bounds__(1024, 4) hybrid_kernel(
    const float* __restrict__ x, const float* __restrict__ W1,
    const float* __restrict__ b1, const float* __restrict__ W2,
    const float* __restrict__ b2, const float* __restrict__ W3,
    const float* __restrict__ b3, float* __restrict__ out, int B)
{
    __shared__ LdsU lds;
    const int tid  = threadIdx.x;
    const int wave = tid >> 6, lane = tid & 63;
    const int row0 = blockIdx.x * BMB;

    // A addressing: lane owns row (wave*16 + (lane&15)), k-offset (lane>>4)*8
    const int kl = (lane >> 4) << 3;
    int arow = row0 + wave * 16 + (lane & 15);
    arow = arow < B ? arow : B - 1;                  // B % 256 == 0 in practice
    const float* abase = x + (size_t)arow * KDIM + kl;

    const f32x4 z4 = {0.f, 0.f, 0.f, 0.f};

    // issue step-0 A loads first: in flight during W1 staging
    f32x4 c0 = *(const f32x4*)(abase);
    f32x4 c1 = *(const f32x4*)(abase + 4);

    // stage W1 -> LDS in B-frag order: chunk c = (step, n, lane16B)
    for (int c = tid; c < NSTEP * 4 * 64; c += 1024) {
        int s = c >> 8, n = (c >> 6) & 3, l = c & 63;
        int k0  = s * 32 + ((l >> 4) << 3);
        int col = n * 16 + (l & 15);
        f32x4 w0 = z4, w1 = z4;
        if (k0 < KDIM) {                             // tail zero-fill (784%8==0)
            const float* p = W1 + (size_t)col * KDIM + k0;
            w0 = *(const f32x4*)p;
            w1 = *(const f32x4*)(p + 4);
        }
        lds.bfr[c] = pack8(w0, w1);
    }

    f32x4 acc[4];
    #pragma unroll
    for (int n = 0; n < 4; ++n)
        #pragma unroll
        for (int j = 0; j < 4; ++j) acc[n][j] = 0.f;

    // raw barrier: drain only LDS writes; A loads stay in flight
    asm volatile("s_waitcnt lgkmcnt(0)" ::: "memory");
    __builtin_amdgcn_s_barrier();
    __builtin_amdgcn_sched_barrier(0);

    // barrier-free main loop: global->reg A, LDS B (read-only), 4 MFMA / step
    #define STEP(s, u0, u1)                                                        \
        {                                                                          \
            s16x8 af = asfrag(pack8(u0, u1));                                      \
            const uint4* bp = &lds.bfr[(s) * 256 + lane];                          \
            _Pragma("unroll")                                                      \
            for (int n = 0; n < 4; ++n)                                            \
                acc[n] = __builtin_amdgcn_mfma_f32_16x16x32_bf16(                  \
                    af, asfrag(bp[n * 64]), acc[n], 0, 0, 0);                      \
        }

    for (int s = 0; s < 23; ++s) {                   // prefetch s+1 unguarded
        f32x4 n0 = *(const f32x4*)(abase + (s + 1) * 32);
        f32x4 n1 = *(const f32x4*)(abase + (s + 1) * 32 + 4);
        STEP(s, c0, c1);
        c0 = n0; c1 = n1;
    }
    {                                                // s=23: guarded prefetch of 24
        f32x4 n0 = z4, n1 = z4;
        if (kl < KDIM - 768) {                       // lanes with k<784 only
            n0 = *(const f32x4*)(abase + 768);
            n1 = *(const f32x4*)(abase + 772);
        }
        STEP(23, c0, c1);
        c0 = n0; c1 = n1;
    }
    STEP(24, c0, c1);
    #undef STEP

    __syncthreads();                                 // all B-frag reads done; reuse LDS

    // h1 = relu(acc + b1); C layout (m89): col = n*16+(lane&15), row = (lane>>4)*4+j
    #pragma unroll
    for (int n = 0; n < 4; ++n) {
        int c = n * 16 + (lane & 15);
        float bias = b1[c];
        #pragma unroll
        for (int j = 0; j < 4; ++j) {
            int r = wave * 16 + (lane >> 4) * 4 + j;
            lds.t.h1[r * H1STR + c] = fmaxf(acc[n][j] + bias, 0.f);
        }
    }
    __syncthreads();

    // layers 2+3: row = tid&255, q = tid>>8 (wave-uniform)
    {
        const int row = tid & 255, q = tid >> 8;
        const float* h1p = &lds.t.h1[row * H1STR];
        f32x4 hv[16];
        #pragma unroll
        for (int k4 = 0; k4 < 16; ++k4) hv[k4] = *(const f32x4*)(h1p + k4 * 4);
        float a1 = 0.f, a2 = 0.f;
        #pragma unroll
        for (int jj = 0; jj < 4; ++jj) {
            int j2 = q * 4 + jj;
            float s = b2[j2];
            #pragma unroll
            for (int k4 = 0; k4 < 16; ++k4) {
                const f32x4 w = *(const f32x4*)(W2 + j2 * 64 + k4 * 4);
                s = fmaf(hv[k4].x, w.x, s); s = fmaf(hv[k4].y, w.y, s);
                s = fmaf(hv[k4].z, w.z, s); s = fmaf(hv[k4].w, w.w, s);
            }
            s = fmaxf(s, 0.f);
            a1 = fmaf(s, W3[16 + j2], a1);
            a2 = fmaf(s, W3[32 + j2], a2);
        }
        lds.t.part[q][row][0] = a1;
        lds.t.part[q][row][1] = a2;
    }
    __syncthreads();

    if (tid < BMB) {
        int grow = row0 + tid;
        if (grow < B) {
            float a1 = b3[1] + lds.t.part[0][tid][0] + lds.t.part[1][tid][0]
                             + lds.t.part[2][tid][0] + lds.t.part[3][tid][0];
            float a2 = b3[2] + lds.t.part[0][tid][1] + lds.t.part[1][tid][1]
                             + lds.t.part[2][tid][1] + lds.t.part[3][tid][1];
            float t1 = 1.f - 2.f / (__expf(2.f * a1) + 1.f);   // tanh
            float t2 = 1.f - 2.f / (__expf(2.f * a2) + 1.f);
            const float PI = 3.14159265358979323846f;
            float z0 = __sinf(PI * t1) * __sinf(PI * t2);
            out[grow] = 1.f / (1.f + __expf(-5.f * z0));
        }
    }
}

extern "C" void kernel_launch(void* const* d_in, const int* in_sizes, int n_in,
                              void* d_out, int out_size, void* d_ws, size_t ws_size,
                              hipStream_t stream) {
    const float* x  = (const float*)d_in[0];
    const float* W1 = (const float*)d_in[1];
    const float* b1 = (const float*)d_in[2];
    const float* W2 = (const float*)d_in[3];
    const float* b2 = (const float*)d_in[4];
    const float* W3 = (const float*)d_in[5];
    const float* b3 = (const float*)d_in[6];
    // d_in[7] = q_params: unused (RZ phases cancel in |psi|^2)
    int B = in_sizes[0] / KDIM;
    int grid = (B + BMB - 1) / BMB;
    hybrid_kernel<<<grid, 1024, 0, stream>>>(x, W1, b1, W2, b2, W3, b3, (float*)d_out, B);
}